// Round 7
// baseline (158.923 us; speedup 1.0000x reference)
//
#include <hip/hip_runtime.h>

#define WST 72   // f16 LDS row stride (144 B)
#define LOG2E 1.44269504f

typedef __attribute__((ext_vector_type(4))) float    f32x4;
typedef __attribute__((ext_vector_type(2))) float    f32x2;
typedef __attribute__((ext_vector_type(8))) _Float16 f16x8;
typedef __attribute__((ext_vector_type(2))) _Float16 f16x2;
typedef __attribute__((ext_vector_type(2))) __fp16   fp16x2_raw;

union U8 { f16x8 v; f16x2 h[4]; };

__device__ __forceinline__ float rcp_f(float x) { return __builtin_amdgcn_rcpf(x); }
__device__ __forceinline__ float exp2_f(float x) { return __builtin_amdgcn_exp2f(x); }
__device__ __forceinline__ float fast_sigmoid(float x) {
    return rcp_f(1.0f + __expf(-x));
}
__device__ __forceinline__ float tanh_exp(float x) {
    return 1.0f - 2.0f * rcp_f(__expf(2.0f * x) + 1.0f);
}
__device__ __forceinline__ f16x2 pkrtz(float a, float b) {
    fp16x2_raw r = __builtin_amdgcn_cvt_pkrtz(a, b);
    return __builtin_bit_cast(f16x2, r);
}

// ---- weight staging: global f32 -> LDS f16 transposed (Wt[c*WST+k] = W[k][c]) ----
__device__ __forceinline__ void wload8(const float* __restrict__ W, int tid, float v[8]) {
#pragma unroll
    for (int i = 0; i < 8; ++i) v[i] = W[tid + i * 512];
}
__device__ __forceinline__ void wstore8(_Float16* Wt, int tid, const float v[8]) {
#pragma unroll
    for (int i = 0; i < 8; ++i) {
        int idx = tid + i * 512;
        Wt[(idx & 63) * WST + (idx >> 6)] = (_Float16)v[i];
    }
}

// B-fragment pair (K=64) straight from a global f32 row-major 64x64 weight.
__device__ __forceinline__ void gfrag(const float* __restrict__ W, int col,
                                      int qd, float scale, f16x8& b0, f16x8& b1) {
#pragma unroll
    for (int t = 0; t < 8; ++t) {
        b0[t] = (_Float16)(W[(qd * 8 + t) * 64 + col] * scale);
        b1[t] = (_Float16)(W[(32 + qd * 8 + t) * 64 + col] * scale);
    }
}

// one 16x16(x64) tile, B from LDS-transposed weights
__device__ __forceinline__ void gemm1(const _Float16* Act, int arow, int qd,
                                      const _Float16* Wt, int bcol, f32x4& acc) {
    f16x8 a0 = *(const f16x8*)(Act + arow * WST + qd * 8);
    f16x8 a1 = *(const f16x8*)(Act + arow * WST + 32 + qd * 8);
    const _Float16* wr = Wt + bcol * WST + qd * 8;
    f16x8 b0 = *(const f16x8*)(wr);
    f16x8 b1 = *(const f16x8*)(wr + 32);
    acc = __builtin_amdgcn_mfma_f32_16x16x32_f16(a0, b0, acc, 0, 0, 0);
    acc = __builtin_amdgcn_mfma_f32_16x16x32_f16(a1, b1, acc, 0, 0, 0);
}

// one 16x16(x64) tile, B direct from global f32
__device__ __forceinline__ void gemm1g(const _Float16* Act, int arow, int qd,
                                       const float* __restrict__ W, int bcol,
                                       f32x4& acc) {
    f16x8 a0 = *(const f16x8*)(Act + arow * WST + qd * 8);
    f16x8 a1 = *(const f16x8*)(Act + arow * WST + 32 + qd * 8);
    f16x8 b0, b1;
    gfrag(W, bcol, qd, 1.0f, b0, b1);
    acc = __builtin_amdgcn_mfma_f32_16x16x32_f16(a0, b0, acc, 0, 0, 0);
    acc = __builtin_amdgcn_mfma_f32_16x16x32_f16(a1, b1, acc, 0, 0, 0);
}

// 2-tile strip (rows arow-frag, cols [colb,+16) and [colb+16,+32)), B from LDS
__device__ __forceinline__ void gemm2(const _Float16* Act, int arow, int qd,
                                      const _Float16* Wt, int colb,
                                      f32x4 acc[2]) {
    f16x8 a0 = *(const f16x8*)(Act + arow * WST + qd * 8);
    f16x8 a1 = *(const f16x8*)(Act + arow * WST + 32 + qd * 8);
#pragma unroll
    for (int cc = 0; cc < 2; ++cc) {
        const _Float16* wr = Wt + (colb + cc * 16) * WST + qd * 8;
        f16x8 b0 = *(const f16x8*)(wr);
        f16x8 b1 = *(const f16x8*)(wr + 32);
        acc[cc] = __builtin_amdgcn_mfma_f32_16x16x32_f16(a0, b0, acc[cc], 0, 0, 0);
        acc[cc] = __builtin_amdgcn_mfma_f32_16x16x32_f16(a1, b1, acc[cc], 0, 0, 0);
    }
}

// ---------------------------------------------------------------------------
// fused_all: block = (n, j-half), grid 256, 512 thr, LDS 77 KB => 2 blocks/CU
// (4 waves/SIMD; R6 probe: 1-block build is VALU-issue bound at 36% efficiency,
// VGPR=104 so registers permit 4 waves - LDS was the only occupancy blocker).
// Unary + binary weights bypass LDS via direct global->reg B-fragments.
// ---------------------------------------------------------------------------
__global__ __launch_bounds__(512, 4) void fused_all_kernel(
    const float* __restrict__ x,
    const float* __restrict__ W_lin, const float* __restrict__ b_lin,
    const float* __restrict__ Wu1,  const float* __restrict__ bu1,
    const float* __restrict__ Wu2,  const float* __restrict__ bu2,
    const float* __restrict__ Wug1, const float* __restrict__ bug1,
    const float* __restrict__ Wug2, const float* __restrict__ bug2,
    const float* __restrict__ Wb1,  const float* __restrict__ bb1,
    const float* __restrict__ Wb2,  const float* __restrict__ bb2,
    const float* __restrict__ Wbg1, const float* __restrict__ bbg1,
    const float* __restrict__ Wbg2, const float* __restrict__ bbg2,
    float* __restrict__ out)
{
    // A: x(f16) -> EPm          B: W_lin -> EPgm
    // C: Wb1P -> Wbg1P          D: Wb1Q -> Wbg1Q -> um
    // SH: h -> Tu(rows 0-31)/Tg(rows 32-63)
    // EQb/EQgb: f32 64x64; alias Red after binary loop
    __shared__ __align__(16) char smem[78848];
    _Float16* A   = (_Float16*)(smem);             // 9216
    _Float16* B   = (_Float16*)(smem + 9216);      // 9216
    _Float16* C   = (_Float16*)(smem + 18432);     // 9216
    _Float16* D   = (_Float16*)(smem + 27648);     // 9216
    _Float16* SH  = (_Float16*)(smem + 36864);     // 9216
    float*    EQb  = (float*)(smem + 46080);       // 16384
    float*    EQgb = (float*)(smem + 62464);       // 16384
    float*    EPm  = (float*)(smem);               // 8704 alias A (x dead after P1)
    float*    EPgm = (float*)(smem + 9216);        // 8704 alias B (W_lin dead after P1)
    float*    um   = (float*)(smem + 27648);       // 8192 alias D (Wbg1Q dead after P4)
    float*    Red  = (float*)(smem + 46080);       // 32768 alias EQb+EQgb (loop-dead)

    int tid = threadIdx.x, w = tid >> 6, l = tid & 63;
    int qd = l >> 4, l16 = l & 15;
    int n = blockIdx.x >> 1, jsel = blockIdx.x & 1;

    // full 64x64 mapping (h, EQ, EQg): 4 row-quarters x 2 col-halves
    int rw = w & 3, ch = w >> 2;
    int arow = rw * 16 + l16;
    int colb = ch * 32 + l16;
    int crow = rw * 16 + qd * 4;

    // 32x64 strip mapping (EP/EPg/Tu/Tg/U/G): 8 tiles, 1 per wave
    int rh = w & 1, cq = w >> 1;
    int srow = rh * 16 + l16;            // local strip row (lane as A-row)
    int scol = cq * 16 + l16;            // strip col
    int scrow = rh * 16 + qd * 4;        // local strip row (C-layout)

    f32x4 acc[2];

    // ---- P0: stage x -> A (f16), W_lin -> B ----
#pragma unroll
    for (int i = 0; i < 4; ++i) {
        int e = tid * 2 + i * 1024;
        f32x2 v = *(const f32x2*)(x + (size_t)n * 4096 + e);
        f16x2 p; p[0] = (_Float16)v[0]; p[1] = (_Float16)v[1];
        *(f16x2*)(A + (e >> 6) * WST + (e & 63)) = p;
    }
    {
        float wv[8];
        wload8(W_lin, tid, wv);
        wstore8(B, tid, wv);
    }
    __syncthreads();

    // ---- P1: h = x@W_lin + b_lin -> SH; stage Wb1P -> C, Wb1Q -> D ----
    {
        float wvP[8], wvQ[8];
        wload8(Wb1, tid, wvP);
        wload8(Wb1 + 4096, tid, wvQ);
#pragma unroll
        for (int cc = 0; cc < 2; ++cc) {
            float bv = b_lin[colb + cc * 16];
            acc[cc] = (f32x4){bv, bv, bv, bv};
        }
        gemm2(A, arow, qd, B, colb, acc);
#pragma unroll
        for (int cc = 0; cc < 2; ++cc)
#pragma unroll
            for (int r = 0; r < 4; ++r)
                SH[(crow + r) * WST + colb + cc * 16] = (_Float16)acc[cc][r];
        wstore8(C, tid, wvP);
        wstore8(D, tid, wvQ);
    }
    __syncthreads();

    // ---- P2: EQ = exp(2(h@Wb1Q)) -> EQb; EP strip -> EPm (alias A);
    //          issue Wbg1 loads (async-stage split: store in P3) ----
    float wvP[8], wvQ[8];
    wload8(Wbg1, tid, wvP);
    wload8(Wbg1 + 4096, tid, wvQ);
    acc[0] = (f32x4){0.f, 0.f, 0.f, 0.f};
    acc[1] = (f32x4){0.f, 0.f, 0.f, 0.f};
    gemm2(SH, arow, qd, D, colb, acc);
#pragma unroll
    for (int cc = 0; cc < 2; ++cc)
#pragma unroll
        for (int r = 0; r < 4; ++r)
            EQb[(crow + r) * 64 + colb + cc * 16] = __expf(2.0f * acc[cc][r]);
    {
        float bv = bb1[scol];
        f32x4 ap = (f32x4){bv, bv, bv, bv};
        gemm1(SH, jsel * 32 + srow, qd, C, scol, ap);
#pragma unroll
        for (int r = 0; r < 4; ++r)
            EPm[(scrow + r) * 68 + scol] = __expf(2.0f * ap[r]);
    }
    __syncthreads();

    // ---- P3: store Wbg1P -> C, Wbg1Q -> D; Tu/Tg pre-activations -> regs
    //          (B-frags direct from global Wu1/Wug1) ----
    f32x4 accu, accg;
    {
        wstore8(C, tid, wvP);
        wstore8(D, tid, wvQ);
        float bv = bu1[scol];
        accu = (f32x4){bv, bv, bv, bv};
        gemm1g(SH, jsel * 32 + srow, qd, Wu1, scol, accu);
        bv = bug1[scol];
        accg = (f32x4){bv, bv, bv, bv};
        gemm1g(SH, jsel * 32 + srow, qd, Wug1, scol, accg);
    }
    __syncthreads();

    // ---- P4: EQg = exp(2(h@Wbg1Q)) -> EQgb; EPg strip -> EPgm (alias B) ----
    acc[0] = (f32x4){0.f, 0.f, 0.f, 0.f};
    acc[1] = (f32x4){0.f, 0.f, 0.f, 0.f};
    gemm2(SH, arow, qd, D, colb, acc);
#pragma unroll
    for (int cc = 0; cc < 2; ++cc)
#pragma unroll
        for (int r = 0; r < 4; ++r)
            EQgb[(crow + r) * 64 + colb + cc * 16] = __expf(2.0f * acc[cc][r]);
    {
        float bv = bbg1[scol];
        f32x4 ap = (f32x4){bv, bv, bv, bv};
        gemm1(SH, jsel * 32 + srow, qd, C, scol, ap);
#pragma unroll
        for (int r = 0; r < 4; ++r)
            EPgm[(scrow + r) * 68 + scol] = __expf(2.0f * ap[r]);
    }
    __syncthreads();

    // ---- P5: Tu -> SH rows 0-31, Tg -> SH rows 32-63 (SH h-reads all done) ----
#pragma unroll
    for (int r = 0; r < 4; ++r) {
        SH[(scrow + r) * WST + scol] = (_Float16)tanh_exp(accu[r]);
        SH[(32 + scrow + r) * WST + scol] = (_Float16)tanh_exp(accg[r]);
    }
    __syncthreads();

    // ---- P6: U = Tu@Wu2+bu2, G = Tg@Wug2+bug2 (global B-frags), um -> D;
    //          binary-weight frags direct global->reg + shfl colsum fold ----
    f16x8 bwm[4][2], bwg[4][2];
    float bim[4], big[4];
    {
        float bv = bu2[scol];
        f32x4 ua = (f32x4){bv, bv, bv, bv};
        gemm1g(SH, srow, qd, Wu2, scol, ua);
        bv = bug2[scol];
        f32x4 ga = (f32x4){bv, bv, bv, bv};
        gemm1g(SH, 32 + srow, qd, Wug2, scol, ga);
#pragma unroll
        for (int r = 0; r < 4; ++r)
            um[(scrow + r) * 64 + scol] = ua[r] * fast_sigmoid(ga[r]);

#pragma unroll
        for (int cc = 0; cc < 4; ++cc) {
            int c = cc * 16 + l16;
            gfrag(Wb2, c, qd, -2.0f, bwm[cc][0], bwm[cc][1]);
            gfrag(Wbg2, c, qd, 2.0f * LOG2E, bwg[cc][0], bwg[cc][1]);
            float sm = 0.0f, sg = 0.0f;
#pragma unroll
            for (int t = 0; t < 8; ++t) {
                sm += (float)bwm[cc][0][t] + (float)bwm[cc][1][t];
                sg += (float)bwg[cc][0][t] + (float)bwg[cc][1][t];
            }
            // reduce across the 4 qd-groups (lanes differing in bits 4,5)
            sm += __shfl_xor(sm, 16); sm += __shfl_xor(sm, 32);
            sg += __shfl_xor(sg, 16); sg += __shfl_xor(sg, 32);
            bim[cc] = bb2[c] - 0.5f * sm;
            big[cc] = -LOG2E * bbg2[c] - 0.5f * sg;
        }
    }
    __syncthreads();

    // =============== binary phase: 2 j-groups x 4 i-ranges (16 ii each) ===============
    int jgrp = w >> 2, iw = w & 3;

    const float* pr  = EPm  + (jgrp * 16 + l16) * 68;
    const float* pgr = EPgm + (jgrp * 16 + l16) * 68;
    f32x4 pm[4], pg[4];
    pm[0] = *(const f32x4*)(pr + qd * 8);
    pm[1] = *(const f32x4*)(pr + qd * 8 + 4);
    pm[2] = *(const f32x4*)(pr + 32 + qd * 8);
    pm[3] = *(const f32x4*)(pr + 32 + qd * 8 + 4);
    pg[0] = *(const f32x4*)(pgr + qd * 8);
    pg[1] = *(const f32x4*)(pgr + qd * 8 + 4);
    pg[2] = *(const f32x4*)(pgr + 32 + qd * 8);
    pg[3] = *(const f32x4*)(pgr + 32 + qd * 8 + 4);

    f32x4 bacc[4];
#pragma unroll
    for (int cc = 0; cc < 4; ++cc) bacc[cc] = (f32x4){0.f, 0.f, 0.f, 0.f};

    for (int ii = iw * 16; ii < iw * 16 + 16; ++ii) {
        const float* qm = EQb  + ii * 64;
        const float* qg = EQgb + ii * 64;
        U8 am[2], ag[2];
#pragma unroll
        for (int kk = 0; kk < 2; ++kk) {
            int cb = kk * 32 + qd * 8;
            f32x4 qa = *(const f32x4*)(qm + cb);
            f32x4 qb = *(const f32x4*)(qm + cb + 4);
            f32x4 ha = *(const f32x4*)(qg + cb);
            f32x4 hb = *(const f32x4*)(qg + cb + 4);
#pragma unroll
            for (int t = 0; t < 2; ++t) {
                // paired reciprocal: 1/a0,1/a1 from one rcp(a0*a1)
                float a0 = __builtin_fmaf(pm[kk*2][2*t],   qa[2*t],   1.0f);
                float a1 = __builtin_fmaf(pm[kk*2][2*t+1], qa[2*t+1], 1.0f);
                float ri = rcp_f(a0 * a1);
                am[kk].h[t]     = pkrtz(ri * a1, ri * a0);
                float b0f = __builtin_fmaf(pm[kk*2+1][2*t],   qb[2*t],   1.0f);
                float b1f = __builtin_fmaf(pm[kk*2+1][2*t+1], qb[2*t+1], 1.0f);
                float rj = rcp_f(b0f * b1f);
                am[kk].h[2 + t] = pkrtz(rj * b1f, rj * b0f);
                float c0 = __builtin_fmaf(pg[kk*2][2*t],   ha[2*t],   1.0f);
                float c1 = __builtin_fmaf(pg[kk*2][2*t+1], ha[2*t+1], 1.0f);
                float rk = rcp_f(c0 * c1);
                ag[kk].h[t]     = pkrtz(rk * c1, rk * c0);
                float d0 = __builtin_fmaf(pg[kk*2+1][2*t],   hb[2*t],   1.0f);
                float d1 = __builtin_fmaf(pg[kk*2+1][2*t+1], hb[2*t+1], 1.0f);
                float rl = rcp_f(d0 * d1);
                ag[kk].h[2 + t] = pkrtz(rl * d1, rl * d0);
            }
        }
#pragma unroll
        for (int cc = 0; cc < 4; ++cc) {
            f32x4 d = {bim[cc], bim[cc], bim[cc], bim[cc]};
            d = __builtin_amdgcn_mfma_f32_16x16x32_f16(am[0].v, bwm[cc][0], d, 0, 0, 0);
            d = __builtin_amdgcn_mfma_f32_16x16x32_f16(am[1].v, bwm[cc][1], d, 0, 0, 0);
            // e = -log2e*G (fold): sigmoid(G) = 1/(1+exp2(e))
            f32x4 e = {big[cc], big[cc], big[cc], big[cc]};
            e = __builtin_amdgcn_mfma_f32_16x16x32_f16(ag[0].v, bwg[cc][0], e, 0, 0, 0);
            e = __builtin_amdgcn_mfma_f32_16x16x32_f16(ag[1].v, bwg[cc][1], e, 0, 0, 0);
            // paired-rcp sigmoid accumulate
            float v0 = exp2_f(e[0]), v1 = exp2_f(e[1]);
            float u0 = 1.0f + v0, u1 = 1.0f + v1;
            float r01 = rcp_f(u0 * u1);
            bacc[cc][0] = __builtin_fmaf(d[0] * u1, r01, bacc[cc][0]);
            bacc[cc][1] = __builtin_fmaf(d[1] * u0, r01, bacc[cc][1]);
            float v2 = exp2_f(e[2]), v3 = exp2_f(e[3]);
            float u2 = 1.0f + v2, u3 = 1.0f + v3;
            float r23 = rcp_f(u2 * u3);
            bacc[cc][2] = __builtin_fmaf(d[2] * u3, r23, bacc[cc][2]);
            bacc[cc][3] = __builtin_fmaf(d[3] * u2, r23, bacc[cc][3]);
        }
    }

    __syncthreads();   // all waves done reading EQb/EQgb before Red overwrites
#pragma unroll
    for (int cc = 0; cc < 4; ++cc)
#pragma unroll
        for (int r = 0; r < 4; ++r)
            Red[(jgrp * 4 + iw) * 1024 + (qd * 4 + r) * 64 + cc * 16 + l16] = bacc[cc][r];
    __syncthreads();

    // reduce 4 i-ranges, add unary, write out (512 thr x 4 f32 = 32x64)
    {
        int e = tid * 4;
        int lr = e >> 6, col = e & 63;
        int g = lr >> 4, rr = lr & 15;
        f32x4 sv = {0.f, 0.f, 0.f, 0.f};
#pragma unroll
        for (int p = 0; p < 4; ++p)
            sv += *(const f32x4*)(Red + (g * 4 + p) * 1024 + rr * 64 + col);
        f32x4 u = *(const f32x4*)(um + lr * 64 + col);
        f32x4 o;
#pragma unroll
        for (int t = 0; t < 4; ++t)
            o[t] = u[t] + sv[t] * (1.0f / 63.0f);
        *(f32x4*)(out + (size_t)n * 4096 + (size_t)(jsel * 32 + lr) * 64 + col) = o;
    }
}

extern "C" void kernel_launch(void* const* d_in, const int* in_sizes, int n_in,
                              void* d_out, int out_size, void* d_ws, size_t ws_size,
                              hipStream_t stream)
{
    (void)in_sizes; (void)n_in; (void)out_size; (void)d_ws; (void)ws_size;
    const float* x     = (const float*)d_in[0];
    const float* W_lin = (const float*)d_in[1];
    const float* b_lin = (const float*)d_in[2];
    const float* Wu1   = (const float*)d_in[3];
    const float* bu1   = (const float*)d_in[4];
    const float* Wu2   = (const float*)d_in[5];
    const float* bu2   = (const float*)d_in[6];
    const float* Wug1  = (const float*)d_in[7];
    const float* bug1  = (const float*)d_in[8];
    const float* Wug2  = (const float*)d_in[9];
    const float* bug2  = (const float*)d_in[10];
    const float* Wb1   = (const float*)d_in[11];
    const float* bb1   = (const float*)d_in[12];
    const float* Wb2   = (const float*)d_in[13];
    const float* bb2   = (const float*)d_in[14];
    const float* Wbg1  = (const float*)d_in[15];
    const float* bbg1  = (const float*)d_in[16];
    const float* Wbg2  = (const float*)d_in[17];
    const float* bbg2  = (const float*)d_in[18];

    hipLaunchKernelGGL(fused_all_kernel, dim3(256), dim3(512), 0, stream,
        x, W_lin, b_lin, Wu1, bu1, Wu2, bu2, Wug1, bug1, Wug2, bug2,
        Wb1, bb1, Wb2, bb2, Wbg1, bbg1, Wbg2, bbg2,
        (float*)d_out);
}

// Round 8
// 121.524 us; speedup vs baseline: 1.3078x; 1.3078x over previous
//
#include <hip/hip_runtime.h>

#define WST 72   // f16 LDS row stride (144 B)
#define LOG2E 1.44269504f

typedef __attribute__((ext_vector_type(4))) float    f32x4;
typedef __attribute__((ext_vector_type(2))) float    f32x2;
typedef __attribute__((ext_vector_type(8))) _Float16 f16x8;
typedef __attribute__((ext_vector_type(2))) _Float16 f16x2;
typedef __attribute__((ext_vector_type(2))) __fp16   fp16x2_raw;

union U8 { f16x8 v; f16x2 h[4]; };

__device__ __forceinline__ float rcp_f(float x) { return __builtin_amdgcn_rcpf(x); }
__device__ __forceinline__ float exp2_f(float x) { return __builtin_amdgcn_exp2f(x); }
__device__ __forceinline__ float fast_sigmoid(float x) {
    return rcp_f(1.0f + __expf(-x));
}
__device__ __forceinline__ float tanh_exp(float x) {
    return 1.0f - 2.0f * rcp_f(__expf(2.0f * x) + 1.0f);
}
__device__ __forceinline__ f16x2 pkrtz(float a, float b) {
    fp16x2_raw r = __builtin_amdgcn_cvt_pkrtz(a, b);
    return __builtin_bit_cast(f16x2, r);
}

// ---- weight staging helpers (coalesced; thread covers column c = tid&63) ----
__device__ __forceinline__ void wload8(const float* __restrict__ W, int tid, float v[8]) {
#pragma unroll
    for (int i = 0; i < 8; ++i) v[i] = W[tid + i * 512];
}
// transposed, stride WST (72)
__device__ __forceinline__ void wstore8(_Float16* Wt, int tid, const float v[8], float scale) {
#pragma unroll
    for (int i = 0; i < 8; ++i) {
        int idx = tid + i * 512;
        Wt[(idx & 63) * WST + (idx >> 6)] = (_Float16)(v[i] * scale);
    }
}
// transposed, stride 64 (compact)
__device__ __forceinline__ void wstore8_64(_Float16* Wt, int tid, const float v[8]) {
#pragma unroll
    for (int i = 0; i < 8; ++i) {
        int idx = tid + i * 512;
        Wt[(idx & 63) * 64 + (idx >> 6)] = (_Float16)v[i];
    }
}

// full-tile gemm strip: A s72, B s72-transposed; cols [colb,+16),[colb+16,+32)
__device__ __forceinline__ void gemm2(const _Float16* Act, int arow, int qd,
                                      const _Float16* Wt, int colb,
                                      f32x4 acc[2]) {
    f16x8 a0 = *(const f16x8*)(Act + arow * WST + qd * 8);
    f16x8 a1 = *(const f16x8*)(Act + arow * WST + 32 + qd * 8);
#pragma unroll
    for (int cc = 0; cc < 2; ++cc) {
        const _Float16* wr = Wt + (colb + cc * 16) * WST + qd * 8;
        f16x8 b0 = *(const f16x8*)(wr);
        f16x8 b1 = *(const f16x8*)(wr + 32);
        acc[cc] = __builtin_amdgcn_mfma_f32_16x16x32_f16(a0, b0, acc[cc], 0, 0, 0);
        acc[cc] = __builtin_amdgcn_mfma_f32_16x16x32_f16(a1, b1, acc[cc], 0, 0, 0);
    }
}
// A s64 (x), B s64-transposed (W_lin): used once in P1
__device__ __forceinline__ void gemm2_64(const _Float16* Act, int arow, int qd,
                                         const _Float16* Wt, int colb,
                                         f32x4 acc[2]) {
    f16x8 a0 = *(const f16x8*)(Act + arow * 64 + qd * 8);
    f16x8 a1 = *(const f16x8*)(Act + arow * 64 + 32 + qd * 8);
#pragma unroll
    for (int cc = 0; cc < 2; ++cc) {
        const _Float16* wr = Wt + (colb + cc * 16) * 64 + qd * 8;
        f16x8 b0 = *(const f16x8*)(wr);
        f16x8 b1 = *(const f16x8*)(wr + 32);
        acc[cc] = __builtin_amdgcn_mfma_f32_16x16x32_f16(a0, b0, acc[cc], 0, 0, 0);
        acc[cc] = __builtin_amdgcn_mfma_f32_16x16x32_f16(a1, b1, acc[cc], 0, 0, 0);
    }
}
// single 16x16 tile: A s72, B s72T
__device__ __forceinline__ void gemm1(const _Float16* Act, int arow, int qd,
                                      const _Float16* Wt, int bcol, f32x4& acc) {
    f16x8 a0 = *(const f16x8*)(Act + arow * WST + qd * 8);
    f16x8 a1 = *(const f16x8*)(Act + arow * WST + 32 + qd * 8);
    const _Float16* wr = Wt + bcol * WST + qd * 8;
    f16x8 b0 = *(const f16x8*)(wr);
    f16x8 b1 = *(const f16x8*)(wr + 32);
    acc = __builtin_amdgcn_mfma_f32_16x16x32_f16(a0, b0, acc, 0, 0, 0);
    acc = __builtin_amdgcn_mfma_f32_16x16x32_f16(a1, b1, acc, 0, 0, 0);
}
// single 16x16 tile: A s72, B s64T
__device__ __forceinline__ void gemm1_b64(const _Float16* Act, int arow, int qd,
                                          const _Float16* Wt, int bcol, f32x4& acc) {
    f16x8 a0 = *(const f16x8*)(Act + arow * WST + qd * 8);
    f16x8 a1 = *(const f16x8*)(Act + arow * WST + 32 + qd * 8);
    const _Float16* wr = Wt + bcol * 64 + qd * 8;
    f16x8 b0 = *(const f16x8*)(wr);
    f16x8 b1 = *(const f16x8*)(wr + 32);
    acc = __builtin_amdgcn_mfma_f32_16x16x32_f16(a0, b0, acc, 0, 0, 0);
    acc = __builtin_amdgcn_mfma_f32_16x16x32_f16(a1, b1, acc, 0, 0, 0);
}

// ---------------------------------------------------------------------------
// fused_all: block = (n, j-half), grid 256, 512 thr, LDS 78848 B => 2 blocks/CU
// possible (VGPR must stay <=128: launch_bounds(512,2) gave 104 in R6 - do NOT
// tighten, (512,4) forces 64+spills). All weight staging coalesced via LDS
// slot rotation; binary loop identical to the R6-verified one.
// Slots: A: Wu1 -> EPm -> um       B: Wug1 -> Wbg1P -> EPgm
//        C: Wb1P -> Wbg1Q         D: Wb1Q -> W1(-2*Wb2)
//        SH: h -> W2(2log2e*Wbg2)
//        EQb area: x(s64)|W_lin(s64T) -> Tu/Tg -> EQb -> Red
//        EQgb area: Wu2(s64T)|Wug2(s64T) -> EQgb -> Red
// ---------------------------------------------------------------------------
__global__ __launch_bounds__(512, 2) void fused_all_kernel(
    const float* __restrict__ x,
    const float* __restrict__ W_lin, const float* __restrict__ b_lin,
    const float* __restrict__ Wu1,  const float* __restrict__ bu1,
    const float* __restrict__ Wu2,  const float* __restrict__ bu2,
    const float* __restrict__ Wug1, const float* __restrict__ bug1,
    const float* __restrict__ Wug2, const float* __restrict__ bug2,
    const float* __restrict__ Wb1,  const float* __restrict__ bb1,
    const float* __restrict__ Wb2,  const float* __restrict__ bb2,
    const float* __restrict__ Wbg1, const float* __restrict__ bbg1,
    const float* __restrict__ Wbg2, const float* __restrict__ bbg2,
    float* __restrict__ out)
{
    __shared__ __align__(16) char smem[78848];
    _Float16* A    = (_Float16*)(smem);            // 9216
    _Float16* B    = (_Float16*)(smem + 9216);     // 9216
    _Float16* C    = (_Float16*)(smem + 18432);    // 9216
    _Float16* D    = (_Float16*)(smem + 27648);    // 9216
    _Float16* SH   = (_Float16*)(smem + 36864);    // 9216
    _Float16* X16  = (_Float16*)(smem + 46080);    // 8192 (x, s64) -> Tu/Tg -> EQb
    _Float16* WL   = (_Float16*)(smem + 54272);    // 8192 (W_lin, s64T)
    _Float16* WU2  = (_Float16*)(smem + 62464);    // 8192 (Wu2, s64T) -> EQgb
    _Float16* WUG2 = (_Float16*)(smem + 70656);    // 8192 (Wug2, s64T)
    _Float16* Tu   = (_Float16*)(smem + 46080);    // 4608 (32x72)
    _Float16* Tg   = (_Float16*)(smem + 50688);    // 4608
    float*    EPm  = (float*)(smem);               // 8704 alias A
    float*    EPgm = (float*)(smem + 9216);        // 8704 alias B
    float*    um   = (float*)(smem);               // 8192 alias A (post-loop)
    float*    EQb  = (float*)(smem + 46080);       // 16384
    float*    EQgb = (float*)(smem + 62464);       // 16384
    float*    Red  = (float*)(smem + 46080);       // 32768 alias EQb+EQgb

    int tid = threadIdx.x, w = tid >> 6, l = tid & 63;
    int qd = l >> 4, l16 = l & 15;
    int n = blockIdx.x >> 1, jsel = blockIdx.x & 1;

    // full 64x64 mapping: 4 row-quarters x 2 col-halves
    int rw = w & 3, ch = w >> 2;
    int arow = rw * 16 + l16;
    int colb = ch * 32 + l16;
    int crow = rw * 16 + qd * 4;

    // 32x64 strip mapping: 2 row-tiles x 4 col-tiles, 1 tile/wave
    int rh = w & 1, cq = w >> 1;
    int srow = rh * 16 + l16;
    int scol = cq * 16 + l16;
    int scrow = rh * 16 + qd * 4;

    f32x4 acc[2];

    // ---- P0: stage x->X16(s64), W_lin->WL(s64T), Wu1->A, Wug1->B,
    //          Wu2->WU2(s64T), Wug2->WUG2(s64T) ----
    {
        float wl[8], u1[8], ug1[8], u2[8], ug2[8];
        wload8(W_lin, tid, wl);
        wload8(Wu1, tid, u1);
        wload8(Wug1, tid, ug1);
        wload8(Wu2, tid, u2);
        wload8(Wug2, tid, ug2);
#pragma unroll
        for (int i = 0; i < 4; ++i) {
            int e = tid * 2 + i * 1024;
            f32x2 v = *(const f32x2*)(x + (size_t)n * 4096 + e);
            f16x2 p; p[0] = (_Float16)v[0]; p[1] = (_Float16)v[1];
            *(f16x2*)(X16 + (e >> 6) * 64 + (e & 63)) = p;
        }
        wstore8_64(WL, tid, wl);
        wstore8(A, tid, u1, 1.0f);
        wstore8(B, tid, ug1, 1.0f);
        wstore8_64(WU2, tid, u2);
        wstore8_64(WUG2, tid, ug2);
    }
    __syncthreads();

    // ---- P1: h = x@W_lin + b_lin -> SH; stage Wb1P->C, Wb1Q->D ----
    {
        float p1[8], q1[8];
        wload8(Wb1, tid, p1);
        wload8(Wb1 + 4096, tid, q1);
#pragma unroll
        for (int cc = 0; cc < 2; ++cc) {
            float bv = b_lin[colb + cc * 16];
            acc[cc] = (f32x4){bv, bv, bv, bv};
        }
        gemm2_64(X16, arow, qd, WL, colb, acc);
#pragma unroll
        for (int cc = 0; cc < 2; ++cc)
#pragma unroll
            for (int r = 0; r < 4; ++r)
                SH[(crow + r) * WST + colb + cc * 16] = (_Float16)acc[cc][r];
        wstore8(C, tid, p1, 1.0f);
        wstore8(D, tid, q1, 1.0f);
    }
    __syncthreads();

    // ---- P2: Tu/Tg = tanh(h_j@Wu1/Wug1 + b) -> X16 area (x dead);
    //          issue Wbg1 loads (stores in P3/P4) ----
    float bp2[8], bq2[8];
    wload8(Wbg1, tid, bp2);
    wload8(Wbg1 + 4096, tid, bq2);
    {
        float bv = bu1[scol];
        f32x4 au = (f32x4){bv, bv, bv, bv};
        gemm1(SH, jsel * 32 + srow, qd, A, scol, au);
        bv = bug1[scol];
        f32x4 ag = (f32x4){bv, bv, bv, bv};
        gemm1(SH, jsel * 32 + srow, qd, B, scol, ag);
#pragma unroll
        for (int r = 0; r < 4; ++r) {
            Tu[(scrow + r) * WST + scol] = (_Float16)tanh_exp(au[r]);
            Tg[(scrow + r) * WST + scol] = (_Float16)tanh_exp(ag[r]);
        }
    }
    __syncthreads();

    // ---- P3: U=Tu@Wu2, G=Tg@Wug2 -> umr regs; EP = exp(2(h_j@Wb1P+bb1)) -> EPm;
    //          store Wbg1P -> B (Wug1 dead) ----
    float umr[4];
    {
        wstore8(B, tid, bp2, 1.0f);
        float bv = bu2[scol];
        f32x4 ua = (f32x4){bv, bv, bv, bv};
        gemm1_b64(Tu, srow, qd, WU2, scol, ua);
        bv = bug2[scol];
        f32x4 ga = (f32x4){bv, bv, bv, bv};
        gemm1_b64(Tg, srow, qd, WUG2, scol, ga);
#pragma unroll
        for (int r = 0; r < 4; ++r)
            umr[r] = ua[r] * fast_sigmoid(ga[r]);

        bv = bb1[scol];
        f32x4 ep = (f32x4){bv, bv, bv, bv};
        gemm1(SH, jsel * 32 + srow, qd, C, scol, ep);
#pragma unroll
        for (int r = 0; r < 4; ++r)
            EPm[(scrow + r) * 68 + scol] = __expf(2.0f * ep[r]);
    }
    __syncthreads();

    // ---- P4: EQ = exp(2(h@Wb1Q)) -> EQb (full; Tu/Tg dead);
    //          EPg strip -> regs; store Wbg1Q -> C (Wb1P dead) ----
    float epr[4];
    {
        wstore8(C, tid, bq2, 1.0f);
        acc[0] = (f32x4){0.f, 0.f, 0.f, 0.f};
        acc[1] = (f32x4){0.f, 0.f, 0.f, 0.f};
        gemm2(SH, arow, qd, D, colb, acc);
#pragma unroll
        for (int cc = 0; cc < 2; ++cc)
#pragma unroll
            for (int r = 0; r < 4; ++r)
                EQb[(crow + r) * 64 + colb + cc * 16] = __expf(2.0f * acc[cc][r]);

        float bv = bbg1[scol];
        f32x4 eg = (f32x4){bv, bv, bv, bv};
        gemm1(SH, jsel * 32 + srow, qd, B, scol, eg);
#pragma unroll
        for (int r = 0; r < 4; ++r)
            epr[r] = __expf(2.0f * eg[r]);
    }
    __syncthreads();

    // ---- P5: EPgm <- epr (B; Wbg1P dead); EQg = exp(2(h@Wbg1Q)) -> EQgb
    //          (Wu2/Wug2 dead); store W1 = -2*Wb2 -> D (Wb1Q dead) ----
    {
        float m2[8], g2[8];
        wload8(Wb2, tid, m2);
        wload8(Wbg2, tid, g2);
#pragma unroll
        for (int r = 0; r < 4; ++r)
            EPgm[(scrow + r) * 68 + scol] = epr[r];
        acc[0] = (f32x4){0.f, 0.f, 0.f, 0.f};
        acc[1] = (f32x4){0.f, 0.f, 0.f, 0.f};
        gemm2(SH, arow, qd, C, colb, acc);
#pragma unroll
        for (int cc = 0; cc < 2; ++cc)
#pragma unroll
            for (int r = 0; r < 4; ++r)
                EQgb[(crow + r) * 64 + colb + cc * 16] = __expf(2.0f * acc[cc][r]);
        wstore8(D, tid, m2, -2.0f);
        __syncthreads();
        // ---- P6: store W2 = 2log2e*Wbg2 -> SH (h dead after EQg) ----
        wstore8(SH, tid, g2, 2.0f * LOG2E);
    }
    __syncthreads();

    // =============== binary phase: 2 j-groups x 4 i-ranges (16 ii each) ===============
    int jgrp = w >> 2, iw = w & 3;

    // B fragments from LDS-staged scaled weights + shfl colsum fold
    f16x8 bwm[4][2], bwg[4][2];
    float bim[4], big[4];
#pragma unroll
    for (int cc = 0; cc < 4; ++cc) {
        int c = cc * 16 + l16;
#pragma unroll
        for (int kk = 0; kk < 2; ++kk) {
            bwm[cc][kk] = *(const f16x8*)(D  + c * WST + kk * 32 + qd * 8);
            bwg[cc][kk] = *(const f16x8*)(SH + c * WST + kk * 32 + qd * 8);
        }
        float sm = 0.0f, sg = 0.0f;
#pragma unroll
        for (int t = 0; t < 8; ++t) {
            sm += (float)bwm[cc][0][t] + (float)bwm[cc][1][t];
            sg += (float)bwg[cc][0][t] + (float)bwg[cc][1][t];
        }
        sm += __shfl_xor(sm, 16); sm += __shfl_xor(sm, 32);
        sg += __shfl_xor(sg, 16); sg += __shfl_xor(sg, 32);
        bim[cc] = bb2[c] - 0.5f * sm;
        big[cc] = -LOG2E * bbg2[c] - 0.5f * sg;
    }

    const float* pr  = EPm  + (jgrp * 16 + l16) * 68;
    const float* pgr = EPgm + (jgrp * 16 + l16) * 68;
    f32x4 pm[4], pg[4];
    pm[0] = *(const f32x4*)(pr + qd * 8);
    pm[1] = *(const f32x4*)(pr + qd * 8 + 4);
    pm[2] = *(const f32x4*)(pr + 32 + qd * 8);
    pm[3] = *(const f32x4*)(pr + 32 + qd * 8 + 4);
    pg[0] = *(const f32x4*)(pgr + qd * 8);
    pg[1] = *(const f32x4*)(pgr + qd * 8 + 4);
    pg[2] = *(const f32x4*)(pgr + 32 + qd * 8);
    pg[3] = *(const f32x4*)(pgr + 32 + qd * 8 + 4);

    f32x4 bacc[4];
#pragma unroll
    for (int cc = 0; cc < 4; ++cc) bacc[cc] = (f32x4){0.f, 0.f, 0.f, 0.f};

    for (int ii = iw * 16; ii < iw * 16 + 16; ++ii) {
        const float* qm = EQb  + ii * 64;
        const float* qg = EQgb + ii * 64;
        U8 am[2], ag[2];
#pragma unroll
        for (int kk = 0; kk < 2; ++kk) {
            int cb = kk * 32 + qd * 8;
            f32x4 qa = *(const f32x4*)(qm + cb);
            f32x4 qb = *(const f32x4*)(qm + cb + 4);
            f32x4 ha = *(const f32x4*)(qg + cb);
            f32x4 hb = *(const f32x4*)(qg + cb + 4);
#pragma unroll
            for (int t = 0; t < 2; ++t) {
                float a0 = __builtin_fmaf(pm[kk*2][2*t],   qa[2*t],   1.0f);
                float a1 = __builtin_fmaf(pm[kk*2][2*t+1], qa[2*t+1], 1.0f);
                float ri = rcp_f(a0 * a1);
                am[kk].h[t]     = pkrtz(ri * a1, ri * a0);
                float b0f = __builtin_fmaf(pm[kk*2+1][2*t],   qb[2*t],   1.0f);
                float b1f = __builtin_fmaf(pm[kk*2+1][2*t+1], qb[2*t+1], 1.0f);
                float rj = rcp_f(b0f * b1f);
                am[kk].h[2 + t] = pkrtz(rj * b1f, rj * b0f);
                float c0 = __builtin_fmaf(pg[kk*2][2*t],   ha[2*t],   1.0f);
                float c1 = __builtin_fmaf(pg[kk*2][2*t+1], ha[2*t+1], 1.0f);
                float rk = rcp_f(c0 * c1);
                ag[kk].h[t]     = pkrtz(rk * c1, rk * c0);
                float d0 = __builtin_fmaf(pg[kk*2+1][2*t],   hb[2*t],   1.0f);
                float d1 = __builtin_fmaf(pg[kk*2+1][2*t+1], hb[2*t+1], 1.0f);
                float rl = rcp_f(d0 * d1);
                ag[kk].h[2 + t] = pkrtz(rl * d1, rl * d0);
            }
        }
#pragma unroll
        for (int cc = 0; cc < 4; ++cc) {
            f32x4 d = {bim[cc], bim[cc], bim[cc], bim[cc]};
            d = __builtin_amdgcn_mfma_f32_16x16x32_f16(am[0].v, bwm[cc][0], d, 0, 0, 0);
            d = __builtin_amdgcn_mfma_f32_16x16x32_f16(am[1].v, bwm[cc][1], d, 0, 0, 0);
            f32x4 e = {big[cc], big[cc], big[cc], big[cc]};
            e = __builtin_amdgcn_mfma_f32_16x16x32_f16(ag[0].v, bwg[cc][0], e, 0, 0, 0);
            e = __builtin_amdgcn_mfma_f32_16x16x32_f16(ag[1].v, bwg[cc][1], e, 0, 0, 0);
            float v0 = exp2_f(e[0]), v1 = exp2_f(e[1]);
            float u0 = 1.0f + v0, u1 = 1.0f + v1;
            float r01 = rcp_f(u0 * u1);
            bacc[cc][0] = __builtin_fmaf(d[0] * u1, r01, bacc[cc][0]);
            bacc[cc][1] = __builtin_fmaf(d[1] * u0, r01, bacc[cc][1]);
            float v2 = exp2_f(e[2]), v3 = exp2_f(e[3]);
            float u2 = 1.0f + v2, u3 = 1.0f + v3;
            float r23 = rcp_f(u2 * u3);
            bacc[cc][2] = __builtin_fmaf(d[2] * u3, r23, bacc[cc][2]);
            bacc[cc][3] = __builtin_fmaf(d[3] * u2, r23, bacc[cc][3]);
        }
    }

    __syncthreads();   // EQ/EQg reads done before Red overwrites; EPm dead
#pragma unroll
    for (int cc = 0; cc < 4; ++cc)
#pragma unroll
        for (int r = 0; r < 4; ++r)
            Red[(jgrp * 4 + iw) * 1024 + (qd * 4 + r) * 64 + cc * 16 + l16] = bacc[cc][r];
    // um from regs -> A area (EPm dead: pm already in registers)
#pragma unroll
    for (int r = 0; r < 4; ++r)
        um[(scrow + r) * 64 + scol] = umr[r];
    __syncthreads();

    // reduce 4 i-ranges, add unary, write out (512 thr x 4 f32 = 32x64)
    {
        int e = tid * 4;
        int lr = e >> 6, col = e & 63;
        int g = lr >> 4, rr = lr & 15;
        f32x4 sv = {0.f, 0.f, 0.f, 0.f};
#pragma unroll
        for (int p = 0; p < 4; ++p)
            sv += *(const f32x4*)(Red + (g * 4 + p) * 1024 + rr * 64 + col);
        f32x4 u = *(const f32x4*)(um + lr * 64 + col);
        f32x4 o;
#pragma unroll
        for (int t = 0; t < 4; ++t)
            o[t] = u[t] + sv[t] * (1.0f / 63.0f);
        *(f32x4*)(out + (size_t)n * 4096 + (size_t)(jsel * 32 + lr) * 64 + col) = o;
    }
}

extern "C" void kernel_launch(void* const* d_in, const int* in_sizes, int n_in,
                              void* d_out, int out_size, void* d_ws, size_t ws_size,
                              hipStream_t stream)
{
    (void)in_sizes; (void)n_in; (void)out_size; (void)d_ws; (void)ws_size;
    const float* x     = (const float*)d_in[0];
    const float* W_lin = (const float*)d_in[1];
    const float* b_lin = (const float*)d_in[2];
    const float* Wu1   = (const float*)d_in[3];
    const float* bu1   = (const float*)d_in[4];
    const float* Wu2   = (const float*)d_in[5];
    const float* bu2   = (const float*)d_in[6];
    const float* Wug1  = (const float*)d_in[7];
    const float* bug1  = (const float*)d_in[8];
    const float* Wug2  = (const float*)d_in[9];
    const float* bug2  = (const float*)d_in[10];
    const float* Wb1   = (const float*)d_in[11];
    const float* bb1   = (const float*)d_in[12];
    const float* Wb2   = (const float*)d_in[13];
    const float* bb2   = (const float*)d_in[14];
    const float* Wbg1  = (const float*)d_in[15];
    const float* bbg1  = (const float*)d_in[16];
    const float* Wbg2  = (const float*)d_in[17];
    const float* bbg2  = (const float*)d_in[18];

    hipLaunchKernelGGL(fused_all_kernel, dim3(256), dim3(512), 0, stream,
        x, W_lin, b_lin, Wu1, bu1, Wu2, bu2, Wug1, bug1, Wug2, bug2,
        Wb1, bb1, Wb2, bb2, Wbg1, bbg1, Wbg2, bbg2,
        (float*)d_out);
}

// Round 9
// 114.832 us; speedup vs baseline: 1.3840x; 1.0583x over previous
//
#include <hip/hip_runtime.h>

#define WST 72   // f16 LDS row stride (144 B = 9*16: aligned, benign banks)
#define LOG2E 1.44269504f

typedef __attribute__((ext_vector_type(4))) float    f32x4;
typedef __attribute__((ext_vector_type(2))) float    f32x2;
typedef __attribute__((ext_vector_type(8))) _Float16 f16x8;
typedef __attribute__((ext_vector_type(2))) _Float16 f16x2;
typedef __attribute__((ext_vector_type(2))) __fp16   fp16x2_raw;

union U8 { f16x8 v; f16x2 h[4]; };

__device__ __forceinline__ float rcp_f(float x) { return __builtin_amdgcn_rcpf(x); }
__device__ __forceinline__ float exp2_f(float x) { return __builtin_amdgcn_exp2f(x); }
__device__ __forceinline__ float fast_sigmoid(float x) {
    return rcp_f(1.0f + __expf(-x));
}
__device__ __forceinline__ float tanh_exp(float x) {
    return 1.0f - 2.0f * rcp_f(__expf(2.0f * x) + 1.0f);
}
__device__ __forceinline__ f16x2 pkrtz(float a, float b) {
    fp16x2_raw r = __builtin_amdgcn_cvt_pkrtz(a, b);
    return __builtin_bit_cast(f16x2, r);
}

// ---- weight staging: global f32 -> LDS f16 transposed (Wt[c*WST+k] = W[k][c]) ----
__device__ __forceinline__ void wload8(const float* __restrict__ W, int tid, float v[8]) {
#pragma unroll
    for (int i = 0; i < 8; ++i) v[i] = W[tid + i * 512];
}
__device__ __forceinline__ void wstore8(_Float16* Wt, int tid, const float v[8], float scale) {
#pragma unroll
    for (int i = 0; i < 8; ++i) {
        int idx = tid + i * 512;
        Wt[(idx & 63) * WST + (idx >> 6)] = (_Float16)(v[i] * scale);
    }
}
__device__ __forceinline__ void wload16(const float* __restrict__ W, int t256, float v[16]) {
#pragma unroll
    for (int i = 0; i < 16; ++i) v[i] = W[t256 + i * 256];
}

// one 16x16(x64) strip of a 64x64x64 GEMM: wave covers rows [arow..), cols
// [colb, colb+16) and [colb+16, colb+32). acc pre-loaded with bias.
__device__ __forceinline__ void gemm2(const _Float16* Act, int arow, int qd,
                                      const _Float16* Wt, int colb,
                                      f32x4 acc[2]) {
    f16x8 a0 = *(const f16x8*)(Act + arow * WST + qd * 8);
    f16x8 a1 = *(const f16x8*)(Act + arow * WST + 32 + qd * 8);
#pragma unroll
    for (int cc = 0; cc < 2; ++cc) {
        const _Float16* wr = Wt + (colb + cc * 16) * WST + qd * 8;
        f16x8 b0 = *(const f16x8*)(wr);
        f16x8 b1 = *(const f16x8*)(wr + 32);
        acc[cc] = __builtin_amdgcn_mfma_f32_16x16x32_f16(a0, b0, acc[cc], 0, 0, 0);
        acc[cc] = __builtin_amdgcn_mfma_f32_16x16x32_f16(a1, b1, acc[cc], 0, 0, 0);
    }
}

// One binary-phase i-row: tanh/gate A-fragments from EQ/EQg + 8 MFMA + gated
// accumulate into BACC. Macro (not fn) so two expansions per loop iteration
// stay in one scheduling region with fully independent chains (ILP x2 at the
// fixed 2 waves/SIMD occupancy - R6: 36% issue efficiency single-chain).
#define BINARY_II(II, BACC) do {                                              \
    const float* qm_ = EQb  + (II) * 64;                                      \
    const float* qg_ = EQgb + (II) * 64;                                      \
    U8 am_[2], ag_[2];                                                        \
    _Pragma("unroll")                                                         \
    for (int kk = 0; kk < 2; ++kk) {                                          \
        int cb_ = kk * 32 + qd * 8;                                           \
        f32x4 qa_ = *(const f32x4*)(qm_ + cb_);                               \
        f32x4 qb_ = *(const f32x4*)(qm_ + cb_ + 4);                           \
        f32x4 ha_ = *(const f32x4*)(qg_ + cb_);                               \
        f32x4 hb_ = *(const f32x4*)(qg_ + cb_ + 4);                           \
        _Pragma("unroll")                                                     \
        for (int t = 0; t < 2; ++t) {                                         \
            float a0_ = __builtin_fmaf(pm[kk*2][2*t],   qa_[2*t],   1.0f);    \
            float a1_ = __builtin_fmaf(pm[kk*2][2*t+1], qa_[2*t+1], 1.0f);    \
            float ri_ = rcp_f(a0_ * a1_);                                     \
            am_[kk].h[t]     = pkrtz(ri_ * a1_, ri_ * a0_);                   \
            float b0_ = __builtin_fmaf(pm[kk*2+1][2*t],   qb_[2*t],   1.0f);  \
            float b1_ = __builtin_fmaf(pm[kk*2+1][2*t+1], qb_[2*t+1], 1.0f);  \
            float rj_ = rcp_f(b0_ * b1_);                                     \
            am_[kk].h[2 + t] = pkrtz(rj_ * b1_, rj_ * b0_);                   \
            float c0_ = __builtin_fmaf(pg[kk*2][2*t],   ha_[2*t],   1.0f);    \
            float c1_ = __builtin_fmaf(pg[kk*2][2*t+1], ha_[2*t+1], 1.0f);    \
            float rk_ = rcp_f(c0_ * c1_);                                     \
            ag_[kk].h[t]     = pkrtz(rk_ * c1_, rk_ * c0_);                   \
            float d0_ = __builtin_fmaf(pg[kk*2+1][2*t],   hb_[2*t],   1.0f);  \
            float d1_ = __builtin_fmaf(pg[kk*2+1][2*t+1], hb_[2*t+1], 1.0f);  \
            float rl_ = rcp_f(d0_ * d1_);                                     \
            ag_[kk].h[2 + t] = pkrtz(rl_ * d1_, rl_ * d0_);                   \
        }                                                                     \
    }                                                                         \
    _Pragma("unroll")                                                         \
    for (int cc = 0; cc < 4; ++cc) {                                          \
        f32x4 d_ = {bim[cc], bim[cc], bim[cc], bim[cc]};                      \
        d_ = __builtin_amdgcn_mfma_f32_16x16x32_f16(am_[0].v, bwm[cc][0], d_, 0, 0, 0); \
        d_ = __builtin_amdgcn_mfma_f32_16x16x32_f16(am_[1].v, bwm[cc][1], d_, 0, 0, 0); \
        f32x4 e_ = {big[cc], big[cc], big[cc], big[cc]};                      \
        e_ = __builtin_amdgcn_mfma_f32_16x16x32_f16(ag_[0].v, bwg[cc][0], e_, 0, 0, 0); \
        e_ = __builtin_amdgcn_mfma_f32_16x16x32_f16(ag_[1].v, bwg[cc][1], e_, 0, 0, 0); \
        float v0_ = exp2_f(e_[0]), v1_ = exp2_f(e_[1]);                       \
        float u0_ = 1.0f + v0_, u1_ = 1.0f + v1_;                             \
        float r01_ = rcp_f(u0_ * u1_);                                        \
        BACC[cc][0] = __builtin_fmaf(d_[0] * u1_, r01_, BACC[cc][0]);         \
        BACC[cc][1] = __builtin_fmaf(d_[1] * u0_, r01_, BACC[cc][1]);         \
        float v2_ = exp2_f(e_[2]), v3_ = exp2_f(e_[3]);                       \
        float u2_ = 1.0f + v2_, u3_ = 1.0f + v3_;                             \
        float r23_ = rcp_f(u2_ * u3_);                                        \
        BACC[cc][2] = __builtin_fmaf(d_[2] * u3_, r23_, BACC[cc][2]);         \
        BACC[cc][3] = __builtin_fmaf(d_[3] * u2_, r23_, BACC[cc][3]);         \
    }                                                                         \
} while (0)

// ---------------------------------------------------------------------------
// fused_all: block = (n, j-half), 512 thr / 8 waves, 1 block/CU (occupancy
// axis exhausted: R3/R5/R7/R8 all null-or-worse). R4 structure + binary loop
// unrolled ii x2 with dual accumulators for in-wave ILP.
// ---------------------------------------------------------------------------
__global__ __launch_bounds__(512, 2) void fused_all_kernel(
    const float* __restrict__ x,
    const float* __restrict__ W_lin, const float* __restrict__ b_lin,
    const float* __restrict__ Wu1,  const float* __restrict__ bu1,
    const float* __restrict__ Wu2,  const float* __restrict__ bu2,
    const float* __restrict__ Wug1, const float* __restrict__ bug1,
    const float* __restrict__ Wug2, const float* __restrict__ bug2,
    const float* __restrict__ Wb1,  const float* __restrict__ bb1,
    const float* __restrict__ Wb2,  const float* __restrict__ bb2,
    const float* __restrict__ Wbg1, const float* __restrict__ bbg1,
    const float* __restrict__ Wbg2, const float* __restrict__ bbg2,
    float* __restrict__ out)
{
    __shared__ __align__(16) char smem[152576];
    _Float16* WLs = (_Float16*)(smem);             // W_lin(T) -> Tu(+0)/Tg(+2304 elems)
    _Float16* SX  = (_Float16*)(smem + 9216);      // x(f16) -> Wu2(T)
    _Float16* SH  = (_Float16*)(smem + 18432);     // h (64x72 f16)
    _Float16* W1  = (_Float16*)(smem + 27648);     // Wb1P -> -2*Wb2
    _Float16* W2  = (_Float16*)(smem + 36864);     // Wb1Q -> 2log2e*Wbg2
    _Float16* W3  = (_Float16*)(smem + 46080);     // Wbg1P
    _Float16* W4  = (_Float16*)(smem + 55296);     // Wbg1Q
    _Float16* W5  = (_Float16*)(smem + 64512);     // Wu1
    _Float16* W6  = (_Float16*)(smem + 73728);     // Wug1
    _Float16* W7  = (_Float16*)(smem + 82944);     // Wug2(T)
    float*    EPm  = (float*)(smem + 92160);       // 32x68 f32 (8704 B)
    float*    EPgm = (float*)(smem + 100864);      // 32x68 f32
    float*    EQb  = (float*)(smem + 109568);      // 64x64 f32 (16384 B)
    float*    EQgb = (float*)(smem + 125952);      // 64x64 f32
    float*    um32 = (float*)(smem + 142336);      // 32x64 f32 (8192 B)
    float*    csP  = (float*)(smem + 150528);      // [8][64] f32 partials
    float*    Red  = (float*)(smem);               // 32768 B alias WLs..W1 (binary-dead)

    int tid = threadIdx.x, w = tid >> 6, l = tid & 63;
    int qd = l >> 4, l16 = l & 15;
    int n = blockIdx.x >> 1, jsel = blockIdx.x & 1;

    // full 64x64 gemm mapping: 4 row-quarters x 2 col-halves
    int rw = w & 3, ch = w >> 2;
    int arow = rw * 16 + l16;
    int colb = ch * 32 + l16;
    int crow = rw * 16 + qd * 4;

    // 32x64 strip mapping (P2 own-strip / P3): s = w&3
    int s = w & 3;
    int lr16 = (s & 1) * 16;
    int cb32 = (s >> 1) * 32;
    bool loW = (w < 4);                  // wave-uniform

    f32x4 acc[2];

    // ---- P0: stage x -> SX (f16), W_lin -> WLs ----
#pragma unroll
    for (int i = 0; i < 4; ++i) {
        int e = tid * 2 + i * 1024;
        f32x2 v = *(const f32x2*)(x + (size_t)n * 4096 + e);
        f16x2 p; p[0] = (_Float16)v[0]; p[1] = (_Float16)v[1];
        *(f16x2*)(SX + (e >> 6) * WST + (e & 63)) = p;
    }
    {
        float wv[8];
        wload8(W_lin, tid, wv);
        wstore8(WLs, tid, wv, 1.0f);
    }
    __syncthreads();

    // ---- P1: h = x@W_lin + b_lin -> SH; stage all 6 first-layer halves ----
    {
        float wv0[8], wv1[8], wv2[8], wv3[8], wv4[8], wv5[8];
        wload8(Wb1, tid, wv0);
        wload8(Wb1 + 4096, tid, wv1);
        wload8(Wbg1, tid, wv2);
        wload8(Wbg1 + 4096, tid, wv3);
        wload8(Wu1, tid, wv4);
        wload8(Wug1, tid, wv5);
#pragma unroll
        for (int cc = 0; cc < 2; ++cc) {
            float bv = b_lin[colb + cc * 16];
            acc[cc] = (f32x4){bv, bv, bv, bv};
        }
        gemm2(SX, arow, qd, WLs, colb, acc);
#pragma unroll
        for (int cc = 0; cc < 2; ++cc)
#pragma unroll
            for (int r = 0; r < 4; ++r)
                SH[(crow + r) * WST + colb + cc * 16] = (_Float16)acc[cc][r];
        wstore8(W1, tid, wv0, 1.0f);
        wstore8(W2, tid, wv1, 1.0f);
        wstore8(W3, tid, wv2, 1.0f);
        wstore8(W4, tid, wv3, 1.0f);
        wstore8(W5, tid, wv4, 1.0f);
        wstore8(W6, tid, wv5, 1.0f);
    }
    __syncthreads();

    // ---- P2 (mega): 4 independent gemm chains per wave, one barrier ----
    {
        float wu2v[8], wug2v[8];
        wload8(Wu2, tid, wu2v);
        wload8(Wug2, tid, wug2v);

        // EQ = exp(2*(h@Wb1Q)), no bias
        acc[0] = (f32x4){0.f, 0.f, 0.f, 0.f};
        acc[1] = (f32x4){0.f, 0.f, 0.f, 0.f};
        gemm2(SH, arow, qd, W2, colb, acc);
#pragma unroll
        for (int cc = 0; cc < 2; ++cc)
#pragma unroll
            for (int r = 0; r < 4; ++r)
                EQb[(crow + r) * 64 + colb + cc * 16] = __expf(2.0f * acc[cc][r]);

        // EQg = exp(2*(h@Wbg1Q)), no bias
        f32x4 accg[2];
        accg[0] = (f32x4){0.f, 0.f, 0.f, 0.f};
        accg[1] = (f32x4){0.f, 0.f, 0.f, 0.f};
        gemm2(SH, arow, qd, W4, colb, accg);
#pragma unroll
        for (int cc = 0; cc < 2; ++cc)
#pragma unroll
            for (int r = 0; r < 4; ++r)
                EQgb[(crow + r) * 64 + colb + cc * 16] = __expf(2.0f * accg[cc][r]);

        // own-strip work on rows jsel*32 + [lr16, lr16+16)
        const _Float16* Wp = loW ? W1 : W3;      // Wb1P : Wbg1P
        const _Float16* Wt = loW ? W5 : W6;      // Wu1  : Wug1
        const float* bp = loW ? bb1 : bbg1;
        const float* bt = loW ? bu1 : bug1;
        float* EPdst = loW ? EPm : EPgm;
        _Float16* Tdst = loW ? WLs : (WLs + 2304);  // Tu / Tg (32x72 each)

        f32x4 accp[2];
#pragma unroll
        for (int cc = 0; cc < 2; ++cc) {
            float bv = bp[cb32 + cc * 16 + l16];
            accp[cc] = (f32x4){bv, bv, bv, bv};
        }
        gemm2(SH, jsel * 32 + lr16 + l16, qd, Wp, cb32 + l16, accp);
#pragma unroll
        for (int cc = 0; cc < 2; ++cc)
#pragma unroll
            for (int r = 0; r < 4; ++r)
                EPdst[(lr16 + qd * 4 + r) * 68 + cb32 + cc * 16 + l16] =
                    __expf(2.0f * accp[cc][r]);

        f32x4 acct[2];
#pragma unroll
        for (int cc = 0; cc < 2; ++cc) {
            float bv = bt[cb32 + cc * 16 + l16];
            acct[cc] = (f32x4){bv, bv, bv, bv};
        }
        gemm2(SH, jsel * 32 + lr16 + l16, qd, Wt, cb32 + l16, acct);
#pragma unroll
        for (int cc = 0; cc < 2; ++cc)
#pragma unroll
            for (int r = 0; r < 4; ++r)
                Tdst[(lr16 + qd * 4 + r) * WST + cb32 + cc * 16 + l16] =
                    (_Float16)tanh_exp(acct[cc][r]);

        wstore8(SX, tid, wu2v, 1.0f);
        wstore8(W7, tid, wug2v, 1.0f);
    }
    __syncthreads();

    // ---- P3: waves 0-3: U/G/um; waves 4-7: binary-weight staging + csum ----
    if (loW) {
        f32x4 ua[2], ga[2];
#pragma unroll
        for (int cc = 0; cc < 2; ++cc) {
            float bv = bu2[cb32 + cc * 16 + l16];
            ua[cc] = (f32x4){bv, bv, bv, bv};
        }
        gemm2(WLs, lr16 + l16, qd, SX, cb32 + l16, ua);
#pragma unroll
        for (int cc = 0; cc < 2; ++cc) {
            float bv = bug2[cb32 + cc * 16 + l16];
            ga[cc] = (f32x4){bv, bv, bv, bv};
        }
        gemm2(WLs + 2304, lr16 + l16, qd, W7, cb32 + l16, ga);
#pragma unroll
        for (int cc = 0; cc < 2; ++cc)
#pragma unroll
            for (int r = 0; r < 4; ++r)
                um32[(lr16 + qd * 4 + r) * 64 + cb32 + cc * 16 + l16] =
                    ua[cc][r] * fast_sigmoid(ga[cc][r]);
    } else {
        int tid2 = tid - 256;                    // 0..255
        float wm[16], wg[16];
        wload16(Wb2, tid2, wm);
        wload16(Wbg2, tid2, wg);
        float csm = 0.0f, csg = 0.0f;
#pragma unroll
        for (int i = 0; i < 16; ++i) {
            int idx = tid2 + i * 256;
            int o = (idx & 63) * WST + (idx >> 6);
            _Float16 a = (_Float16)(wm[i] * -2.0f);
            _Float16 b = (_Float16)(wg[i] * (2.0f * LOG2E));
            W1[o] = a;
            W2[o] = b;
            csm += (float)a;
            csg += (float)b;
        }
        int q = tid2 >> 6, c = tid2 & 63;        // 4 partials per col per matrix
        csP[q * 64 + c] = csm;
        csP[256 + q * 64 + c] = csg;
    }
    __syncthreads();

    // =============== binary phase: ii+=2, dual accumulators (ILP x2) ===============
    int jgrp = w >> 2, iw = w & 3;

    // B fragments from staged weights
    f16x8 bwm[4][2], bwg[4][2];
#pragma unroll
    for (int cc = 0; cc < 4; ++cc)
#pragma unroll
        for (int kk = 0; kk < 2; ++kk) {
            bwm[cc][kk] = *(const f16x8*)(W1 + (cc * 16 + l16) * WST + kk * 32 + qd * 8);
            bwg[cc][kk] = *(const f16x8*)(W2 + (cc * 16 + l16) * WST + kk * 32 + qd * 8);
        }
    float bim[4], big[4];
#pragma unroll
    for (int cc = 0; cc < 4; ++cc) {
        int c = cc * 16 + l16;
        bim[cc] = bb2[c] -
            0.5f * (csP[c] + csP[64 + c] + csP[128 + c] + csP[192 + c]);
        big[cc] = -LOG2E * bbg2[c] -
            0.5f * (csP[256 + c] + csP[320 + c] + csP[384 + c] + csP[448 + c]);
    }

    // P fragments (loop-invariant, register-resident)
    const float* pr  = EPm  + (jgrp * 16 + l16) * 68;
    const float* pgr = EPgm + (jgrp * 16 + l16) * 68;
    f32x4 pm[4], pg[4];
    pm[0] = *(const f32x4*)(pr + qd * 8);
    pm[1] = *(const f32x4*)(pr + qd * 8 + 4);
    pm[2] = *(const f32x4*)(pr + 32 + qd * 8);
    pm[3] = *(const f32x4*)(pr + 32 + qd * 8 + 4);
    pg[0] = *(const f32x4*)(pgr + qd * 8);
    pg[1] = *(const f32x4*)(pgr + qd * 8 + 4);
    pg[2] = *(const f32x4*)(pgr + 32 + qd * 8);
    pg[3] = *(const f32x4*)(pgr + 32 + qd * 8 + 4);

    f32x4 bacc0[4], bacc1[4];
#pragma unroll
    for (int cc = 0; cc < 4; ++cc) {
        bacc0[cc] = (f32x4){0.f, 0.f, 0.f, 0.f};
        bacc1[cc] = (f32x4){0.f, 0.f, 0.f, 0.f};
    }

    for (int ii = iw * 16; ii < iw * 16 + 16; ii += 2) {
        BINARY_II(ii,     bacc0);
        BINARY_II(ii + 1, bacc1);
    }
#pragma unroll
    for (int cc = 0; cc < 4; ++cc) bacc0[cc] += bacc1[cc];

    __syncthreads();   // all waves done with W1/W2 frags + EQ/EP reads
#pragma unroll
    for (int cc = 0; cc < 4; ++cc)
#pragma unroll
        for (int r = 0; r < 4; ++r)
            Red[(jgrp * 4 + iw) * 1024 + (qd * 4 + r) * 64 + cc * 16 + l16] = bacc0[cc][r];
    __syncthreads();

    // reduce 4 i-ranges, add unary, write out
    {
        int e = tid * 4;                 // 512 thr x 4 = 2048 = 32x64
        int lr = e >> 6, col = e & 63;
        int g = lr >> 4, rr = lr & 15;
        f32x4 sv = {0.f, 0.f, 0.f, 0.f};
#pragma unroll
        for (int p = 0; p < 4; ++p)
            sv += *(const f32x4*)(Red + (g * 4 + p) * 1024 + rr * 64 + col);
        f32x4 u = *(const f32x4*)(um32 + lr * 64 + col);
        f32x4 o;
#pragma unroll
        for (int t = 0; t < 4; ++t)
            o[t] = u[t] + sv[t] * (1.0f / 63.0f);
        *(f32x4*)(out + (size_t)n * 4096 + (size_t)(jsel * 32 + lr) * 64 + col) = o;
    }
}

extern "C" void kernel_launch(void* const* d_in, const int* in_sizes, int n_in,
                              void* d_out, int out_size, void* d_ws, size_t ws_size,
                              hipStream_t stream)
{
    (void)in_sizes; (void)n_in; (void)out_size; (void)d_ws; (void)ws_size;
    const float* x     = (const float*)d_in[0];
    const float* W_lin = (const float*)d_in[1];
    const float* b_lin = (const float*)d_in[2];
    const float* Wu1   = (const float*)d_in[3];
    const float* bu1   = (const float*)d_in[4];
    const float* Wu2   = (const float*)d_in[5];
    const float* bu2   = (const float*)d_in[6];
    const float* Wug1  = (const float*)d_in[7];
    const float* bug1  = (const float*)d_in[8];
    const float* Wug2  = (const float*)d_in[9];
    const float* bug2  = (const float*)d_in[10];
    const float* Wb1   = (const float*)d_in[11];
    const float* bb1   = (const float*)d_in[12];
    const float* Wb2   = (const float*)d_in[13];
    const float* bb2   = (const float*)d_in[14];
    const float* Wbg1  = (const float*)d_in[15];
    const float* bbg1  = (const float*)d_in[16];
    const float* Wbg2  = (const float*)d_in[17];
    const float* bbg2  = (const float*)d_in[18];

    hipLaunchKernelGGL(fused_all_kernel, dim3(256), dim3(512), 0, stream,
        x, W_lin, b_lin, Wu1, bu1, Wu2, bu2, Wug1, bug1, Wug2, bug2,
        Wb1, bb1, Wb2, bb2, Wbg1, bbg1, Wbg2, bbg2,
        (float*)d_out);
}